// Round 5
// baseline (1572.853 us; speedup 1.0000x reference)
//
#include <hip/hip_runtime.h>
#include <math.h>

#define BB 2
#define CDIM 256
#define NHEADS 8
#define HD 32
#define HH 40
#define WW 40
#define NN 1600
#define C3 768
#define SCALE 0.17677669529663687f  // 1/sqrt(32)
#define RT 8            // rows per block in attention kernels
#define NRT (NN / RT)   // 200 row-tiles

// ---------- helpers ----------
__device__ inline unsigned fkey(float f) {
    unsigned u = __float_as_uint(f);
    return (u & 0x80000000u) ? ~u : (u | 0x80000000u);
}
__device__ inline float finv(unsigned u) {
    unsigned v = (u & 0x80000000u) ? (u ^ 0x80000000u) : ~u;
    return __uint_as_float(v);
}

// reduce-scatter 16 values over 64 lanes; lane l gets total of value bitrev4(l&15)
__device__ inline float reduce_scatter16(float (&v)[16], int lane) {
#pragma unroll
    for (int step = 0; step < 4; step++) {
        const int off = 1 << step;
        const bool up = (lane >> step) & 1;
        const int h = 16 >> (step + 1);
#pragma unroll
        for (int i = 0; i < h; i++) {
            float send = up ? v[i] : v[h + i];
            float recv = __shfl_xor(send, off);
            float keep = up ? v[h + i] : v[i];
            v[i] = keep + recv;
        }
    }
    float r = v[0];
    r += __shfl_xor(r, 16);
    r += __shfl_xor(r, 32);
    return r;
}
__device__ inline int scatter_d16(int lane) {
    int l = lane & 15;
    return ((l & 1) << 3) | ((l & 2) << 1) | ((l & 4) >> 1) | ((l & 8) >> 3);
}

// ---------- 1x1 conv: block covers 256 s-positions x 4 output channels ----------
__global__ __launch_bounds__(256) void conv1x1_kernel(const float* __restrict__ x,
                                                      const float* __restrict__ w,
                                                      const float* __restrict__ bias,
                                                      float* __restrict__ out) {
    int blk = blockIdx.x;
    int st = blk % 7;
    int t2 = blk / 7;
    int ocg = t2 % (C3 / 4);
    int b = t2 / (C3 / 4);
    int s = st * 256 + threadIdx.x;
    if (s >= NN) return;
    int oc0 = ocg * 4;
    const float* xb = x + (size_t)b * CDIM * NN + s;
    const float* w0 = w + (size_t)oc0 * CDIM;
    float a0 = bias[oc0], a1 = bias[oc0 + 1], a2 = bias[oc0 + 2], a3 = bias[oc0 + 3];
#pragma unroll 4
    for (int ic = 0; ic < CDIM; ic++) {
        float xv = xb[(size_t)ic * NN];
        a0 += w0[ic] * xv;
        a1 += w0[CDIM + ic] * xv;
        a2 += w0[2 * CDIM + ic] * xv;
        a3 += w0[3 * CDIM + ic] * xv;
    }
    float* ob = out + ((size_t)b * C3 + oc0) * NN + s;
    ob[0] = a0; ob[NN] = a1; ob[2 * NN] = a2; ob[3 * NN] = a3;
}

// ---------- depthwise 3x3 pad1 ----------
__global__ __launch_bounds__(256) void dwconv_kernel(const float* __restrict__ in,
                                                     const float* __restrict__ w,
                                                     const float* __restrict__ bias,
                                                     float* __restrict__ out) {
    int idx = blockIdx.x * 256 + threadIdx.x;
    int s = idx % NN;
    int t = idx / NN;
    int c = t % C3;
    int b = t / C3;
    int y = s / WW, xx = s % WW;
    const float* ib = in + ((size_t)b * C3 + c) * NN;
    const float* wr = w + (size_t)c * 9;
    float acc = bias[c];
#pragma unroll
    for (int ky = 0; ky < 3; ky++) {
        int iy = y + ky - 1;
        if (iy < 0 || iy >= HH) continue;
#pragma unroll
        for (int kx = 0; kx < 3; kx++) {
            int ix = xx + kx - 1;
            if (ix < 0 || ix >= WW) continue;
            acc += wr[ky * 3 + kx] * ib[iy * WW + ix];
        }
    }
    out[idx] = acc;
}

// ---------- phase 1: entropy; att in regs (d-chunked QK), no max-subtraction ----------
__global__ __launch_bounds__(256) void entropy_kernel(const float* __restrict__ qkv,
                                                      float* __restrict__ ent) {
    int blk = blockIdx.x;      // bh*NRT + rt
    int rt = blk % NRT;
    int bh = blk / NRT;
    int h = bh % NHEADS, b = bh / NHEADS;
    int row0 = rt * RT;
    __shared__ float Qs[RT][HD];
    int tid = threadIdx.x;
    const float* qb = qkv + ((size_t)b * C3 + h * HD) * NN;
    const float* kb = qkv + ((size_t)b * C3 + CDIM + h * HD) * NN;
    {
        int r = tid >> 5, d = tid & 31;
        Qs[r][d] = qb[(size_t)d * NN + row0 + r];
    }
    __syncthreads();
    int w = tid >> 6, lane = tid & 63;
    int lr0 = 2 * w, lr1 = lr0 + 1;

    float av0[25], av1[25];
#pragma unroll
    for (int kt = 0; kt < 25; kt++) { av0[kt] = 0.f; av1[kt] = 0.f; }
#pragma unroll 1
    for (int dc = 0; dc < 4; dc++) {
        float q0[8], q1[8];
#pragma unroll
        for (int i = 0; i < 8; i++) { q0[i] = Qs[lr0][dc * 8 + i]; q1[i] = Qs[lr1][dc * 8 + i]; }
        const float* kbase = kb + (size_t)(dc * 8) * NN;
#pragma unroll
        for (int kt = 0; kt < 25; kt++) {
            int j = kt * 64 + lane;
            float a0 = av0[kt], a1 = av1[kt];
#pragma unroll
            for (int i = 0; i < 8; i++) {
                float kv = kbase[(size_t)i * NN + j];
                a0 += q0[i] * kv;
                a1 += q1[i] * kv;
            }
            av0[kt] = a0; av1[kt] = a1;
        }
    }
    float S0 = 0.f, T0 = 0.f, S1 = 0.f, T1 = 0.f;
#pragma unroll
    for (int kt = 0; kt < 25; kt++) {
        float a0 = av0[kt] * SCALE, a1 = av1[kt] * SCALE;
        float e0 = __expf(a0), e1 = __expf(a1);
        S0 += e0; T0 += e0 * a0;
        S1 += e1; T1 += e1 * a1;
    }
#pragma unroll
    for (int o = 1; o < 64; o <<= 1) {
        S0 += __shfl_xor(S0, o); T0 += __shfl_xor(T0, o);
        S1 += __shfl_xor(S1, o); T1 += __shfl_xor(T1, o);
    }
    if (lane == 0) {
        ent[(size_t)bh * NN + row0 + lr0] = logf(S0) - T0 / S0;
        ent[(size_t)bh * NN + row0 + lr1] = logf(S1) - T1 / S1;
    }
}

// ---------- gate ----------
__global__ void gate_kernel(const float* __restrict__ ent_rows,
                            const float* __restrict__ g1w, const float* __restrict__ g1b,
                            const float* __restrict__ g2w, const float* __restrict__ g2b,
                            int* __restrict__ keep) {
    int bh = blockIdx.x;
    int tid = threadIdx.x;
    __shared__ float red[4];
    float ls = 0.f;
    for (int j = tid; j < NN; j += 256) ls += ent_rows[bh * NN + j];
    for (int o = 32; o > 0; o >>= 1) ls += __shfl_down(ls, o);
    int lane = tid & 63, wid = tid >> 6;
    if (lane == 0) red[wid] = ls;
    __syncthreads();
    if (tid == 0) {
        float ent = (red[0] + red[1] + red[2] + red[3]) / (float)NN;
        float val = g2b[0];
#pragma unroll
        for (int j = 0; j < 16; j++) {
            float hid = ent * g1w[j] + g1b[j];
            if (hid < 0.f) hid = 0.f;
            val += hid * g2w[j];
        }
        float ratio = 0.9f / (1.f + expf(-val)) + 0.1f;
        int kp = (int)ceilf(ratio * (float)NN);
        if (kp < 1) kp = 1;
        if (kp > NN) kp = NN;
        keep[bh] = kp;
    }
}

// ---------- phase 2: QK in regs (d-chunked), bitwise binary-search kth, PV d-chunked ----------
__global__ __launch_bounds__(256) void sparse_attn_kernel(const float* __restrict__ qkv,
                                                          const int* __restrict__ keep,
                                                          float* __restrict__ oht) {
    int blk = blockIdx.x;
    int rt = blk % NRT;
    int bh = blk / NRT;
    int h = bh % NHEADS, b = bh / NHEADS;
    int row0 = rt * RT;
    __shared__ float Qs[RT][HD];
    int tid = threadIdx.x;
    const float* qb = qkv + ((size_t)b * C3 + h * HD) * NN;
    const float* kb = qkv + ((size_t)b * C3 + CDIM + h * HD) * NN;
    const float* vb = qkv + ((size_t)b * C3 + 2 * CDIM + h * HD) * NN;
    {
        int r = tid >> 5, d = tid & 31;
        Qs[r][d] = qb[(size_t)d * NN + row0 + r];
    }
    __syncthreads();
    int w = tid >> 6, lane = tid & 63;
    int lr0 = 2 * w, lr1 = lr0 + 1;

    // ---- QK^T, d-chunked to bound register pressure ----
    float av0[25], av1[25];
#pragma unroll
    for (int kt = 0; kt < 25; kt++) { av0[kt] = 0.f; av1[kt] = 0.f; }
#pragma unroll 1
    for (int dc = 0; dc < 4; dc++) {
        float q0[8], q1[8];
#pragma unroll
        for (int i = 0; i < 8; i++) { q0[i] = Qs[lr0][dc * 8 + i]; q1[i] = Qs[lr1][dc * 8 + i]; }
        const float* kbase = kb + (size_t)(dc * 8) * NN;
#pragma unroll
        for (int kt = 0; kt < 25; kt++) {
            int j = kt * 64 + lane;
            float a0 = av0[kt], a1 = av1[kt];
#pragma unroll
            for (int i = 0; i < 8; i++) {
                float kv = kbase[(size_t)i * NN + j];
                a0 += q0[i] * kv;
                a1 += q1[i] * kv;
            }
            av0[kt] = a0; av1[kt] = a1;
        }
    }
    // scale + convert to monotone keys, in place
#pragma unroll
    for (int kt = 0; kt < 25; kt++) {
        av0[kt] = __uint_as_float(fkey(av0[kt] * SCALE));
        av1[kt] = __uint_as_float(fkey(av1[kt] * SCALE));
    }

    // ---- kth-largest via 32-step bitwise binary search (no LDS, no atomics) ----
    int want = keep[bh];
    unsigned kb0 = 0u, kb1 = 0u;
    for (int bit = 31; bit >= 0; --bit) {
        unsigned t0 = kb0 | (1u << bit), t1 = kb1 | (1u << bit);
        int c0 = 0, c1 = 0;
#pragma unroll
        for (int kt = 0; kt < 25; kt++) {
            c0 += (__float_as_uint(av0[kt]) >= t0);
            c1 += (__float_as_uint(av1[kt]) >= t1);
        }
#pragma unroll
        for (int o = 1; o < 64; o <<= 1) {
            c0 += __shfl_xor(c0, o);
            c1 += __shfl_xor(c1, o);
        }
        if (c0 >= want) kb0 = t0;
        if (c1 >= want) kb1 = t1;
    }

    // ---- sparse softmax weights (raw exp, no max-sub), in place ----
    float S0 = 0.f, S1 = 0.f;
#pragma unroll
    for (int kt = 0; kt < 25; kt++) {
        unsigned u0 = __float_as_uint(av0[kt]), u1 = __float_as_uint(av1[kt]);
        float p0 = (u0 >= kb0) ? __expf(finv(u0)) : 0.f;
        float p1 = (u1 >= kb1) ? __expf(finv(u1)) : 0.f;
        av0[kt] = p0; av1[kt] = p1;
        S0 += p0; S1 += p1;
    }
#pragma unroll
    for (int o = 1; o < 64; o <<= 1) {
        S0 += __shfl_xor(S0, o);
        S1 += __shfl_xor(S1, o);
    }

    // ---- PV, d-chunked 2x16; register reduce-scatter; direct store ----
#pragma unroll 1
    for (int dc = 0; dc < 2; dc++) {
        float acc0[16], acc1[16];
#pragma unroll
        for (int i = 0; i < 16; i++) { acc0[i] = 0.f; acc1[i] = 0.f; }
        const float* vbase = vb + (size_t)(dc * 16) * NN;
#pragma unroll
        for (int kt = 0; kt < 25; kt++) {
            int j = kt * 64 + lane;
            float p0 = av0[kt], p1 = av1[kt];
#pragma unroll
            for (int i = 0; i < 16; i++) {
                float vv = vbase[(size_t)i * NN + j];
                acc0[i] += p0 * vv;
                acc1[i] += p1 * vv;
            }
        }
        float tot0 = reduce_scatter16(acc0, lane);
        float tot1 = reduce_scatter16(acc1, lane);
        int dd = dc * 16 + scatter_d16(lane);
        size_t base = ((size_t)b * CDIM + h * HD + dd) * NN + row0;
        if (lane < 16) oht[base + lr0] = tot0 / S0;
        else if (lane < 32) oht[base + lr1] = tot1 / S1;
    }
}

// ---------- output projection from oht [b][c][n] ----------
__global__ __launch_bounds__(256) void proj_kernel(const float* __restrict__ oht,
                                                   const float* __restrict__ pw,
                                                   const float* __restrict__ pb,
                                                   float* __restrict__ out) {
    int blk = blockIdx.x;
    int st = blk % 7;
    int t2 = blk / 7;
    int ocg = t2 % (CDIM / 4);
    int b = t2 / (CDIM / 4);
    int s = st * 256 + threadIdx.x;
    if (s >= NN) return;
    int co0 = ocg * 4;
    const float* ib = oht + (size_t)b * CDIM * NN + s;
    const float* w0 = pw + (size_t)co0 * CDIM;
    float a0 = pb[co0], a1 = pb[co0 + 1], a2 = pb[co0 + 2], a3 = pb[co0 + 3];
#pragma unroll 4
    for (int c = 0; c < CDIM; c++) {
        float xv = ib[(size_t)c * NN];
        a0 += w0[c] * xv;
        a1 += w0[CDIM + c] * xv;
        a2 += w0[2 * CDIM + c] * xv;
        a3 += w0[3 * CDIM + c] * xv;
    }
    float* ob = out + ((size_t)b * CDIM + co0) * NN + s;
    ob[0] = a0; ob[NN] = a1; ob[2 * NN] = a2; ob[3 * NN] = a3;
}

extern "C" void kernel_launch(void* const* d_in, const int* in_sizes, int n_in,
                              void* d_out, int out_size, void* d_ws, size_t ws_size,
                              hipStream_t stream) {
    const float* x      = (const float*)d_in[0];
    const float* qkv_w  = (const float*)d_in[1];
    const float* qkv_b  = (const float*)d_in[2];
    const float* pos_w  = (const float*)d_in[3];
    const float* pos_b  = (const float*)d_in[4];
    const float* proj_w = (const float*)d_in[5];
    const float* proj_b = (const float*)d_in[6];
    const float* g1w    = (const float*)d_in[7];
    const float* g1b    = (const float*)d_in[8];
    const float* g2w    = (const float*)d_in[9];
    const float* g2b    = (const float*)d_in[10];
    float* out = (float*)d_out;

    float* ws   = (float*)d_ws;
    float* buf1 = ws;                                  // BB*C3*NN
    float* buf2 = buf1 + (size_t)BB * C3 * NN;         // BB*C3*NN
    float* ent  = buf2 + (size_t)BB * C3 * NN;         // BB*NHEADS*NN
    float* oht  = ent + (size_t)BB * NHEADS * NN;      // BB*CDIM*NN  ([b][c][n])
    int* keep   = (int*)(oht + (size_t)BB * CDIM * NN);

    conv1x1_kernel<<<BB * (C3 / 4) * 7, 256, 0, stream>>>(x, qkv_w, qkv_b, buf1);
    dwconv_kernel<<<BB * C3 * NN / 256, 256, 0, stream>>>(buf1, pos_w, pos_b, buf2);
    entropy_kernel<<<NHEADS * BB * NRT, 256, 0, stream>>>(buf2, ent);
    gate_kernel<<<BB * NHEADS, 256, 0, stream>>>(ent, g1w, g1b, g2w, g2b, keep);
    sparse_attn_kernel<<<NHEADS * BB * NRT, 256, 0, stream>>>(buf2, keep, oht);
    proj_kernel<<<BB * (CDIM / 4) * 7, 256, 0, stream>>>(oht, proj_w, proj_b, out);
}

// Round 6
// 556.472 us; speedup vs baseline: 2.8265x; 2.8265x over previous
//
#include <hip/hip_runtime.h>
#include <math.h>

#define BB 2
#define CDIM 256
#define NHEADS 8
#define HD 32
#define HH 40
#define WW 40
#define NN 1600
#define C3 768
#define SCALE 0.17677669529663687f  // 1/sqrt(32)
#define RTE 8            // rows per block, entropy kernel
#define RTS 4            // rows per block, sparse kernel

// ---------- helpers ----------
__device__ inline unsigned fkey(float f) {
    unsigned u = __float_as_uint(f);
    return (u & 0x80000000u) ? ~u : (u | 0x80000000u);
}
__device__ inline float finv(unsigned u) {
    unsigned v = (u & 0x80000000u) ? (u ^ 0x80000000u) : ~u;
    return __uint_as_float(v);
}

// ---------- 1x1 conv: block covers 256 s-positions x 4 output channels ----------
__global__ __launch_bounds__(256) void conv1x1_kernel(const float* __restrict__ x,
                                                      const float* __restrict__ w,
                                                      const float* __restrict__ bias,
                                                      float* __restrict__ out) {
    int blk = blockIdx.x;
    int st = blk % 7;
    int t2 = blk / 7;
    int ocg = t2 % (C3 / 4);
    int b = t2 / (C3 / 4);
    int s = st * 256 + threadIdx.x;
    if (s >= NN) return;
    int oc0 = ocg * 4;
    const float* xb = x + (size_t)b * CDIM * NN + s;
    const float* w0 = w + (size_t)oc0 * CDIM;
    float a0 = bias[oc0], a1 = bias[oc0 + 1], a2 = bias[oc0 + 2], a3 = bias[oc0 + 3];
#pragma unroll 4
    for (int ic = 0; ic < CDIM; ic++) {
        float xv = xb[(size_t)ic * NN];
        a0 += w0[ic] * xv;
        a1 += w0[CDIM + ic] * xv;
        a2 += w0[2 * CDIM + ic] * xv;
        a3 += w0[3 * CDIM + ic] * xv;
    }
    float* ob = out + ((size_t)b * C3 + oc0) * NN + s;
    ob[0] = a0; ob[NN] = a1; ob[2 * NN] = a2; ob[3 * NN] = a3;
}

// ---------- depthwise 3x3 pad1 ----------
__global__ __launch_bounds__(256) void dwconv_kernel(const float* __restrict__ in,
                                                     const float* __restrict__ w,
                                                     const float* __restrict__ bias,
                                                     float* __restrict__ out) {
    int idx = blockIdx.x * 256 + threadIdx.x;
    int s = idx % NN;
    int t = idx / NN;
    int c = t % C3;
    int b = t / C3;
    int y = s / WW, xx = s % WW;
    const float* ib = in + ((size_t)b * C3 + c) * NN;
    const float* wr = w + (size_t)c * 9;
    float acc = bias[c];
#pragma unroll
    for (int ky = 0; ky < 3; ky++) {
        int iy = y + ky - 1;
        if (iy < 0 || iy >= HH) continue;
#pragma unroll
        for (int kx = 0; kx < 3; kx++) {
            int ix = xx + kx - 1;
            if (ix < 0 || ix >= WW) continue;
            acc += wr[ky * 3 + kx] * ib[iy * WW + ix];
        }
    }
    out[idx] = acc;
}

// ---------- phase 1: streaming entropy (no att storage, raw exp) ----------
__global__ __launch_bounds__(256) void entropy_kernel(const float* __restrict__ qkv,
                                                      float* __restrict__ ent) {
    int blk = blockIdx.x;      // bh*(NN/RTE) + rt
    int rt = blk % (NN / RTE);
    int bh = blk / (NN / RTE);
    int h = bh % NHEADS, b = bh / NHEADS;
    int row0 = rt * RTE;
    __shared__ float Qs[RTE][HD];
    int tid = threadIdx.x;
    const float* qb = qkv + ((size_t)b * C3 + h * HD) * NN;
    const float* kb = qkv + ((size_t)b * C3 + CDIM + h * HD) * NN;
    {
        int r = tid >> 5, d = tid & 31;
        Qs[r][d] = qb[(size_t)d * NN + row0 + r];
    }
    __syncthreads();
    int w = tid >> 6, lane = tid & 63;
    int lr0 = 2 * w, lr1 = lr0 + 1;
    float q0[HD], q1[HD];
#pragma unroll
    for (int d = 0; d < HD; d++) { q0[d] = Qs[lr0][d]; q1[d] = Qs[lr1][d]; }
    float S0 = 0.f, T0 = 0.f, S1 = 0.f, T1 = 0.f;
#pragma unroll 1
    for (int kt = 0; kt < 25; kt++) {
        int j = kt * 64 + lane;
        float a0 = 0.f, a1 = 0.f;
#pragma unroll
        for (int dc = 0; dc < 4; dc++) {
            float kc[8];
#pragma unroll
            for (int i = 0; i < 8; i++) kc[i] = kb[(size_t)(dc * 8 + i) * NN + j];
#pragma unroll
            for (int i = 0; i < 8; i++) {
                a0 += q0[dc * 8 + i] * kc[i];
                a1 += q1[dc * 8 + i] * kc[i];
            }
        }
        a0 *= SCALE; a1 *= SCALE;
        float e0 = __expf(a0), e1 = __expf(a1);
        S0 += e0; T0 += e0 * a0;
        S1 += e1; T1 += e1 * a1;
    }
#pragma unroll
    for (int o = 1; o < 64; o <<= 1) {
        S0 += __shfl_xor(S0, o); T0 += __shfl_xor(T0, o);
        S1 += __shfl_xor(S1, o); T1 += __shfl_xor(T1, o);
    }
    if (lane == 0) {
        ent[(size_t)bh * NN + row0 + lr0] = logf(S0) - T0 / S0;
        ent[(size_t)bh * NN + row0 + lr1] = logf(S1) - T1 / S1;
    }
}

// ---------- gate ----------
__global__ void gate_kernel(const float* __restrict__ ent_rows,
                            const float* __restrict__ g1w, const float* __restrict__ g1b,
                            const float* __restrict__ g2w, const float* __restrict__ g2b,
                            int* __restrict__ keep) {
    int bh = blockIdx.x;
    int tid = threadIdx.x;
    __shared__ float red[4];
    float ls = 0.f;
    for (int j = tid; j < NN; j += 256) ls += ent_rows[bh * NN + j];
    for (int o = 32; o > 0; o >>= 1) ls += __shfl_down(ls, o);
    int lane = tid & 63, wid = tid >> 6;
    if (lane == 0) red[wid] = ls;
    __syncthreads();
    if (tid == 0) {
        float ent = (red[0] + red[1] + red[2] + red[3]) / (float)NN;
        float val = g2b[0];
#pragma unroll
        for (int j = 0; j < 16; j++) {
            float hid = ent * g1w[j] + g1b[j];
            if (hid < 0.f) hid = 0.f;
            val += hid * g2w[j];
        }
        float ratio = 0.9f / (1.f + expf(-val)) + 0.1f;
        int kp = (int)ceilf(ratio * (float)NN);
        if (kp < 1) kp = 1;
        if (kp > NN) kp = NN;
        keep[bh] = kp;
    }
}

// ---------- phase 2: att in LDS (4 rows), reg-cached radix keys, fused S+PV ----------
__global__ __launch_bounds__(128) void sparse_attn_kernel(const float* __restrict__ qkv,
                                                          const int* __restrict__ keep,
                                                          float* __restrict__ oht) {
    int blk = blockIdx.x;
    int rt = blk % (NN / RTS);
    int bh = blk / (NN / RTS);
    int h = bh % NHEADS, b = bh / NHEADS;
    int row0 = rt * RTS;
    __shared__ float att[RTS][NN];       // 25.6 KB
    __shared__ unsigned hist[RTS][256];  // 4 KB
    __shared__ float Qs[RTS][HD];        // 0.5 KB
    int tid = threadIdx.x;               // 0..127
    const float* qb = qkv + ((size_t)b * C3 + h * HD) * NN;
    const float* kb = qkv + ((size_t)b * C3 + CDIM + h * HD) * NN;
    const float* vb = qkv + ((size_t)b * C3 + 2 * CDIM + h * HD) * NN;
    {
        int r = tid >> 5, d = tid & 31;
        Qs[r][d] = qb[(size_t)d * NN + row0 + r];
    }
    int want = keep[bh];
    __syncthreads();
    int w = tid >> 6, lane = tid & 63;
    int lr0 = 2 * w, lr1 = lr0 + 1;
    float q0[HD], q1[HD];
#pragma unroll
    for (int d = 0; d < HD; d++) { q0[d] = Qs[lr0][d]; q1[d] = Qs[lr1][d]; }

    // ---- QK^T into LDS att rows; track per-row max ----
    float m0 = -1e30f, m1 = -1e30f;
    for (int kt = 0; kt < 25; kt++) {
        int j = kt * 64 + lane;
        float kc[HD];
#pragma unroll
        for (int d = 0; d < HD; d++) kc[d] = kb[(size_t)d * NN + j];
        float a0 = 0.f, a1 = 0.f;
#pragma unroll
        for (int d = 0; d < HD; d++) { a0 += q0[d] * kc[d]; a1 += q1[d] * kc[d]; }
        a0 *= SCALE; a1 *= SCALE;
        att[lr0][j] = a0;
        att[lr1][j] = a1;
        m0 = fmaxf(m0, a0); m1 = fmaxf(m1, a1);
    }
#pragma unroll
    for (int off = 1; off < 64; off <<= 1) {
        m0 = fmaxf(m0, __shfl_xor(m0, off));
        m1 = fmaxf(m1, __shfl_xor(m1, off));
    }

    // ---- cache monotone keys in registers (32 lanes per row; rows in half-waves) ----
    int l = lane & 31;
    int r = (lane < 32) ? lr0 : lr1;
    unsigned kv[50];
#pragma unroll
    for (int k2 = 0; k2 < 50; k2++) kv[k2] = fkey(att[r][k2 * 32 + l]);

    // ---- radix select kth-largest from register keys ----
    unsigned prefixHigh = 0;
    for (int pass = 0; pass < 4; pass++) {
        int shift = 24 - 8 * pass;
#pragma unroll
        for (int i = 0; i < 8; i++) hist[r][248 - 8 * l + i] = 0u;
#pragma unroll
        for (int k2 = 0; k2 < 50; k2++) {
            unsigned u = kv[k2];
            bool ok = (pass == 0) || ((u >> (shift + 8)) == prefixHigh);
            if (ok) atomicAdd(&hist[r][(u >> shift) & 255u], 1u);
        }
        unsigned sch = 0;
#pragma unroll
        for (int i = 0; i < 8; i++) sch += hist[r][248 - 8 * l + i];
        unsigned inc = sch;
#pragma unroll
        for (int dlt = 1; dlt < 32; dlt <<= 1) {
            unsigned tv = __shfl_up(inc, dlt, 32);
            if (l >= dlt) inc += tv;
        }
        unsigned pref = inc - sch;
        bool found = (pref < (unsigned)want) && ((unsigned)want <= inc);
        int bsel = -1, wnew = 0;
        if (found) {
            unsigned want2 = (unsigned)want - pref, cum = 0;
#pragma unroll
            for (int i = 0; i < 8; i++) {
                int bbin = 255 - 8 * l - i;
                unsigned c = hist[r][bbin];
                if (bsel < 0 && cum + c >= want2) { bsel = bbin; wnew = (int)(want2 - cum); }
                cum += c;
            }
        }
        unsigned long long mk = __ballot(found);
        int src = (lane < 32) ? __builtin_ctzll(mk & 0xffffffffULL)
                              : __builtin_ctzll(mk >> 32) + 32;
        bsel = __shfl(bsel, src);
        want = __shfl(wnew, src);
        prefixHigh = (prefixHigh << 8) | (unsigned)bsel;
    }
    float kth = finv(prefixHigh);
    float kth0 = __shfl(kth, 0);
    float kth1 = __shfl(kth, 32);

    // ---- fused sparse softmax + PV (S accumulated inline) ----
    float acc0[HD], acc1[HD];
#pragma unroll
    for (int d = 0; d < HD; d++) { acc0[d] = 0.f; acc1[d] = 0.f; }
    float S0 = 0.f, S1 = 0.f;
    for (int kt = 0; kt < 25; kt++) {
        int j = kt * 64 + lane;
        float a0 = att[lr0][j];
        float a1 = att[lr1][j];
        float p0 = (a0 >= kth0) ? __expf(a0 - m0) : 0.f;
        float p1 = (a1 >= kth1) ? __expf(a1 - m1) : 0.f;
        S0 += p0; S1 += p1;
#pragma unroll
        for (int d = 0; d < HD; d++) {
            float vv = vb[(size_t)d * NN + j];
            acc0[d] += p0 * vv;
            acc1[d] += p1 * vv;
        }
    }
#pragma unroll
    for (int off = 1; off < 64; off <<= 1) {
        S0 += __shfl_xor(S0, off);
        S1 += __shfl_xor(S1, off);
    }

    // ---- reduce acc over the 64 lanes via per-wave LDS scratch (reuses att rows) ----
    float* scratch = &att[lr0][0];  // this wave's 2 rows = 3200 floats; need 64*33=2112
    int dd = lane & 31;
    int jb = (lane < 32) ? 0 : 32;
#pragma unroll
    for (int d = 0; d < HD; d++) scratch[lane * 33 + d] = acc0[d];
    float sum0 = 0.f;
#pragma unroll
    for (int jj = 0; jj < 32; jj++) sum0 += scratch[(jb + jj) * 33 + dd];
    sum0 += __shfl_xor(sum0, 32);
#pragma unroll
    for (int d = 0; d < HD; d++) scratch[lane * 33 + d] = acc1[d];
    float sum1 = 0.f;
#pragma unroll
    for (int jj = 0; jj < 32; jj++) sum1 += scratch[(jb + jj) * 33 + dd];
    sum1 += __shfl_xor(sum1, 32);

    if (lane < 32) {
        size_t base = ((size_t)b * CDIM + h * HD + dd) * NN + row0;
        oht[base + lr0] = sum0 / S0;
        oht[base + lr1] = sum1 / S1;
    }
}

// ---------- output projection from oht [b][c][n] ----------
__global__ __launch_bounds__(256) void proj_kernel(const float* __restrict__ oht,
                                                   const float* __restrict__ pw,
                                                   const float* __restrict__ pb,
                                                   float* __restrict__ out) {
    int blk = blockIdx.x;
    int st = blk % 7;
    int t2 = blk / 7;
    int ocg = t2 % (CDIM / 4);
    int b = t2 / (CDIM / 4);
    int s = st * 256 + threadIdx.x;
    if (s >= NN) return;
    int co0 = ocg * 4;
    const float* ib = oht + (size_t)b * CDIM * NN + s;
    const float* w0 = pw + (size_t)co0 * CDIM;
    float a0 = pb[co0], a1 = pb[co0 + 1], a2 = pb[co0 + 2], a3 = pb[co0 + 3];
#pragma unroll 4
    for (int c = 0; c < CDIM; c++) {
        float xv = ib[(size_t)c * NN];
        a0 += w0[c] * xv;
        a1 += w0[CDIM + c] * xv;
        a2 += w0[2 * CDIM + c] * xv;
        a3 += w0[3 * CDIM + c] * xv;
    }
    float* ob = out + ((size_t)b * CDIM + co0) * NN + s;
    ob[0] = a0; ob[NN] = a1; ob[2 * NN] = a2; ob[3 * NN] = a3;
}

extern "C" void kernel_launch(void* const* d_in, const int* in_sizes, int n_in,
                              void* d_out, int out_size, void* d_ws, size_t ws_size,
                              hipStream_t stream) {
    const float* x      = (const float*)d_in[0];
    const float* qkv_w  = (const float*)d_in[1];
    const float* qkv_b  = (const float*)d_in[2];
    const float* pos_w  = (const float*)d_in[3];
    const float* pos_b  = (const float*)d_in[4];
    const float* proj_w = (const float*)d_in[5];
    const float* proj_b = (const float*)d_in[6];
    const float* g1w    = (const float*)d_in[7];
    const float* g1b    = (const float*)d_in[8];
    const float* g2w    = (const float*)d_in[9];
    const float* g2b    = (const float*)d_in[10];
    float* out = (float*)d_out;

    float* ws   = (float*)d_ws;
    float* buf1 = ws;                                  // BB*C3*NN
    float* buf2 = buf1 + (size_t)BB * C3 * NN;         // BB*C3*NN
    float* ent  = buf2 + (size_t)BB * C3 * NN;         // BB*NHEADS*NN
    float* oht  = ent + (size_t)BB * NHEADS * NN;      // BB*CDIM*NN  ([b][c][n])
    int* keep   = (int*)(oht + (size_t)BB * CDIM * NN);

    conv1x1_kernel<<<BB * (C3 / 4) * 7, 256, 0, stream>>>(x, qkv_w, qkv_b, buf1);
    dwconv_kernel<<<BB * C3 * NN / 256, 256, 0, stream>>>(buf1, pos_w, pos_b, buf2);
    entropy_kernel<<<NHEADS * BB * (NN / RTE), 256, 0, stream>>>(buf2, ent);
    gate_kernel<<<BB * NHEADS, 256, 0, stream>>>(ent, g1w, g1b, g2w, g2b, keep);
    sparse_attn_kernel<<<NHEADS * BB * (NN / RTS), 128, 0, stream>>>(buf2, keep, oht);
    proj_kernel<<<BB * (CDIM / 4) * 7, 256, 0, stream>>>(oht, proj_w, proj_b, out);
}